// Round 23
// baseline (112.451 us; speedup 1.0000x reference)
//
#include <hip/hip_runtime.h>
#include <hip/hip_fp16.h>

#define BB   8
#define CC   64
#define HH   128
#define WW   128
#define OCC  128
#define HWx  (HH*WW)
#define KTOT 576
#define SST  584    // ushort row stride: 576 + 8 (1168 B, 16B-multiple)

typedef __attribute__((ext_vector_type(8))) short short8t;
typedef __attribute__((ext_vector_type(8))) _Float16 half8t;
typedef __attribute__((ext_vector_type(4))) float f32x4;

static __device__ __forceinline__ ushort f2h(float f) {
    __half h = __float2half_rn(f);
    return __half_as_ushort(h);
}

// ---- KFRONT2: ktrans2 (0..2047) + kmain-wf (2048..2335) + split-W (2336..2479)
__global__ __launch_bounds__(256) void kfront2(const float* __restrict__ x,
                                               ushort* __restrict__ xTh,
                                               ushort* __restrict__ xTl,
                                               const float* __restrict__ cw,
                                               ushort* __restrict__ wf,
                                               const float* __restrict__ ow,
                                               ushort* __restrict__ woh,
                                               ushort* __restrict__ wol) {
    int bi  = blockIdx.x;
    int tid = threadIdx.x;

    if (bi < 2048) {
        // ---- role: x NCHW fp32 -> xT_hi (fp16) + xT_lo ((x-hi)*2048, fp16) --
        int bb = bi;
        int b  = bb >> 8;
        int p  = (bb & 255) * 64 + (tid & 63);
        int cg = tid >> 6;
        const float* xb = x + (size_t)b * CC * HWx + p;
        size_t base = ((size_t)b * HWx + p) * 64 + cg * 16;
        short8t h0, h1, l0, l1;
#pragma unroll
        for (int e = 0; e < 8; ++e) {
            float v = xb[(size_t)(cg * 16 + e) * HWx];
            __half h = __float2half_rn(v);
            h0[e] = (short)__half_as_ushort(h);
            l0[e] = (short)f2h((v - __half2float(h)) * 2048.f);
        }
#pragma unroll
        for (int e = 0; e < 8; ++e) {
            float v = xb[(size_t)(cg * 16 + 8 + e) * HWx];
            __half h = __float2half_rn(v);
            h1[e] = (short)__half_as_ushort(h);
            l1[e] = (short)f2h((v - __half2float(h)) * 2048.f);
        }
        *(short8t*)(xTh + base)     = h0;
        *(short8t*)(xTh + base + 8) = h1;
        *(short8t*)(xTl + base)     = l0;
        *(short8t*)(xTl + base + 8) = l1;

    } else if (bi < 2336) {
        // ---- role: conv_w -> fragment-ordered fp16 table (kmain A) ---------
        int i = (bi - 2048) * 256 + tid;    // 0..73727
        int e  = i & 7;
        int t  = i >> 3;
        int l  = t & 63;
        int t2 = t >> 6;                    // wv*18 + ks
        int lr = l & 15, lg = l >> 4;
        int oc = (t2 / 18) * 16 + lr;
        int kg = (t2 % 18) * 32 + lg * 8 + e;
        int c = kg & 63, tap = kg >> 6;
        wf[i] = f2h(cw[oc * 576 + c * 9 + tap]);

    } else {
        // ---- role: off_w -> split fragment-ordered B tables (x1024) --------
        int idx = (bi - 2336) * 256 + tid;  // 0..36863
        int t   = idx / 18432;              // 0=hi, 1=lo
        int r   = idx - t * 18432;
        int nt  = r / 9216;
        int r2  = r - nt * 9216;
        int ks  = r2 / 512;
        int r3  = r2 - ks * 512;
        int l   = r3 >> 3;
        int e   = r3 & 7;
        int k   = ks * 32 + (l >> 4) * 8 + e;
        int tap = k >> 6, c = k & 63;
        int ch  = nt * 16 + (l & 15);
        float val = (ch < 18) ? ow[ch * 576 + c * 9 + tap] * 1024.f : 0.f;
        __half h = __float2half_rn(val);
        if (t == 0) woh[r] = __half_as_ushort(h);
        else        wol[r] = f2h(val - __half2float(h));
    }
}

// ---- KOFFM: offset conv via split-fp16 MFMA (fp32-grade accuracy) ----------
// grid 1024 = (b,i) rows, b = bi&7. 256 thr = 4 waves; wave = 32 pixels.
// out[pix][ch] = (accA*2^-10 + accB*2^-21) + bias;  A rows = pixels (xT hi/lo),
// B cols = channels (woh/wol, x1024). Fragment layouts as verified in kmain.
__global__ __launch_bounds__(256) void koffM(const ushort* __restrict__ xTh,
                                             const ushort* __restrict__ xTl,
                                             const ushort* __restrict__ woh,
                                             const ushort* __restrict__ wol,
                                             const float* __restrict__ off_b,
                                             float* __restrict__ offsT) {
    int tid = threadIdx.x;
    int bi  = blockIdx.x;
    int b   = bi & 7;
    int i   = bi >> 3;
    int wv  = tid >> 6;                // wave: pixels [32wv, 32wv+32)
    int l   = tid & 63;
    int lr  = l & 15, lg = l >> 4;
    const ushort* xh = xTh + (size_t)b * HWx * 64;
    const ushort* xl = xTl + (size_t)b * HWx * 64;

    f32x4 accA[2][2], accB[2][2];
#pragma unroll
    for (int mt = 0; mt < 2; ++mt)
#pragma unroll
        for (int nt = 0; nt < 2; ++nt)
#pragma unroll
            for (int e = 0; e < 4; ++e) { accA[mt][nt][e] = 0.f; accB[mt][nt][e] = 0.f; }

#pragma unroll
    for (int ks = 0; ks < 18; ++ks) {
        int tap = ks >> 1;
        int di = tap / 3, dj = tap - di * 3;
        int si = i + di - 1;
        bool sv = (si >= 0) && (si < HH);
        int c0 = (ks & 1) * 32 + lg * 8;

        half8t Bh0 = *(const half8t*)(woh + ((0 * 18 + ks) * 64 + l) * 8);
        half8t Bl0 = *(const half8t*)(wol + ((0 * 18 + ks) * 64 + l) * 8);
        half8t Bh1 = *(const half8t*)(woh + ((1 * 18 + ks) * 64 + l) * 8);
        half8t Bl1 = *(const half8t*)(wol + ((1 * 18 + ks) * 64 + l) * 8);

#pragma unroll
        for (int mt = 0; mt < 2; ++mt) {
            int j  = wv * 32 + mt * 16 + lr;
            int sj = j + dj - 1;
            bool v = sv && (sj >= 0) && (sj < WW);
            half8t Ah = {0, 0, 0, 0, 0, 0, 0, 0};
            half8t Al = {0, 0, 0, 0, 0, 0, 0, 0};
            if (v) {
                size_t ao = ((size_t)(si * WW + sj)) * 64 + c0;
                Ah = *(const half8t*)(xh + ao);
                Al = *(const half8t*)(xl + ao);
            }
            accA[mt][0] = __builtin_amdgcn_mfma_f32_16x16x32_f16(Ah, Bh0, accA[mt][0], 0, 0, 0);
            accA[mt][0] = __builtin_amdgcn_mfma_f32_16x16x32_f16(Ah, Bl0, accA[mt][0], 0, 0, 0);
            accB[mt][0] = __builtin_amdgcn_mfma_f32_16x16x32_f16(Al, Bh0, accB[mt][0], 0, 0, 0);
            accA[mt][1] = __builtin_amdgcn_mfma_f32_16x16x32_f16(Ah, Bh1, accA[mt][1], 0, 0, 0);
            accA[mt][1] = __builtin_amdgcn_mfma_f32_16x16x32_f16(Ah, Bl1, accA[mt][1], 0, 0, 0);
            accB[mt][1] = __builtin_amdgcn_mfma_f32_16x16x32_f16(Al, Bh1, accB[mt][1], 0, 0, 0);
        }
    }

    const float sA = 1.f / 1024.f;
    const float sB = 1.f / (1024.f * 2048.f);
#pragma unroll
    for (int mt = 0; mt < 2; ++mt)
#pragma unroll
        for (int nt = 0; nt < 2; ++nt) {
            int ch = nt * 16 + lr;
            if (ch < 18) {
                float bv = off_b[ch];
#pragma unroll
                for (int e = 0; e < 4; ++e) {
                    int pix = wv * 32 + mt * 16 + lg * 4 + e;
                    float val = accA[mt][nt][e] * sA + accB[mt][nt][e] * sB + bv;
                    offsT[((size_t)(b * HWx) + i * WW + pix) * 18 + ch] = val;
                }
            }
        }
}

static __device__ __forceinline__ __half2 lerp_w(uint ltw, uint rbw, uint lbw, uint rtw,
                                                 __half2 hlt, __half2 hrb,
                                                 __half2 hlb, __half2 hrt) {
    __half2 a;
    a = __hmul2(hlt, __builtin_bit_cast(__half2, ltw));
    a = __hfma2(hrb, __builtin_bit_cast(__half2, rbw), a);
    a = __hfma2(hlb, __builtin_bit_cast(__half2, lbw), a);
    a = __hfma2(hrt, __builtin_bit_cast(__half2, rtw), a);
    return a;
}
static __device__ __forceinline__ uint4 lerp_u4(uint4 lt, uint4 rb, uint4 lb, uint4 rt,
                                                __half2 hlt, __half2 hrb,
                                                __half2 hlb, __half2 hrt) {
    uint4 o;
    o.x = __builtin_bit_cast(uint, lerp_w(lt.x, rb.x, lb.x, rt.x, hlt, hrb, hlb, hrt));
    o.y = __builtin_bit_cast(uint, lerp_w(lt.y, rb.y, lb.y, rt.y, hlt, hrb, hlb, hrt));
    o.z = __builtin_bit_cast(uint, lerp_w(lt.z, rb.z, lb.z, rt.z, hlt, hrb, hlb, hrt));
    o.w = __builtin_bit_cast(uint, lerp_w(lt.w, rb.w, lb.w, rt.w, hlt, hrb, hlb, hrt));
    return o;
}

// ---- K2: fused gather + MFMA; 16-ch grain + frag weights (R22 verbatim) ----
__global__ __launch_bounds__(512, 4) void kmain23(const ushort* __restrict__ xT,
                                                  const float* __restrict__ offsT,
                                                  const ushort* __restrict__ wf,
                                                  const float* __restrict__ conv_b,
                                                  float* __restrict__ out) {
    __shared__ __align__(16) ushort S[32 * SST];   // 37376 B
    int tid = threadIdx.x;                 // 0..511
    int bi  = blockIdx.x;
    int b   = bi & 7;                      // XCD-affine batch
    int rem = bi >> 3;                     // 0..511
    int oi  = rem >> 2;
    int oj0 = (rem & 3) * 32;

    const ushort* xTb  = xT + (size_t)b * HWx * 64;
    const float*  offb = offsT + (size_t)b * HWx * 18;

    int wv = tid >> 6;                     // wave 0..7: oc tile [16wv,16wv+16)
    int l  = tid & 63;
    int lr = l & 15;
    int lg = l >> 4;
    const ushort* wr0 = wf + ((size_t)(wv * 18) * 64 + l) * 8;

    // ---- phase 1: 1152 subtasks = (pix, tap, 16-ch), 2.25/thread ----
#pragma unroll
    for (int it = 0; it < 3; ++it) {
        int s = tid + it * 512;
        if (s >= 1152) break;
        int pix = s / 36;
        int rr  = s - pix * 36;
        int tap = rr >> 2;
        int cg2 = rr & 3;                  // 16-ch group
        int kr = tap / 3, kc = tap - kr * 3;
        int si = oi + ((kr == 0) ? -1 : 0);
        int sj = oj0 + pix + ((kc == 0) ? -1 : 0);
        ushort* Sd = &S[pix * SST + tap * 64 + cg2 * 16];

        if (si < 0 || sj < 0) {
            uint4 z = {0, 0, 0, 0};
            *(uint4*)Sd = z;
            *(uint4*)(Sd + 8) = z;
            continue;
        }
        int n    = ((kr == 0) ? 2 : kr - 1) * 3 + ((kc == 0) ? 2 : kc - 1);
        int pidx = si * WW + sj;
        float ox = offb[pidx * 18 + n];
        float oy = offb[pidx * 18 + 9 + n];
        float px = (float)si + ox;
        float py = (float)sj + oy;
        float fx = floorf(px), fy = floorf(py);
        float pxc   = fminf(fmaxf(px, 0.f), 127.f);
        float pyc   = fminf(fmaxf(py, 0.f), 127.f);
        float qltxf = fminf(fmaxf(fx, 0.f), 127.f);
        float qltyf = fminf(fmaxf(fy, 0.f), 127.f);
        float qrbxf = fminf(fmaxf(fx + 1.f, 0.f), 127.f);
        float qrbyf = fminf(fmaxf(fy + 1.f, 0.f), 127.f);
        int qltx = (int)qltxf, qlty = (int)qltyf;
        int qrbx = (int)qrbxf, qrby = (int)qrbyf;
        int co = cg2 * 16;
        const ushort* plt = xTb + (size_t)(qltx * WW + qlty) * 64 + co;
        const ushort* prb = xTb + (size_t)(qrbx * WW + qrby) * 64 + co;
        const ushort* plb = xTb + (size_t)(qltx * WW + qrby) * 64 + co;
        const ushort* prt = xTb + (size_t)(qrbx * WW + qlty) * 64 + co;
        uint4 lt0 = *(const uint4*)(plt);  uint4 lt1 = *(const uint4*)(plt + 8);
        uint4 rb0 = *(const uint4*)(prb);  uint4 rb1 = *(const uint4*)(prb + 8);
        uint4 lb0 = *(const uint4*)(plb);  uint4 lb1 = *(const uint4*)(plb + 8);
        uint4 rt0 = *(const uint4*)(prt);  uint4 rt1 = *(const uint4*)(prt + 8);

        float glt = (1.f + (qltxf - pxc)) * (1.f + (qltyf - pyc));
        float grb = (1.f - (qrbxf - pxc)) * (1.f - (qrbyf - pyc));
        float glb = (1.f + (qltxf - pxc)) * (1.f - (qrbyf - pyc));
        float grt = (1.f - (qrbxf - pxc)) * (1.f + (qltyf - pyc));
        __half2 hlt = __float2half2_rn(glt);
        __half2 hrb = __float2half2_rn(grb);
        __half2 hlb = __float2half2_rn(glb);
        __half2 hrt = __float2half2_rn(grt);

        uint4 o0 = lerp_u4(lt0, rb0, lb0, rt0, hlt, hrb, hlb, hrt);
        uint4 o1 = lerp_u4(lt1, rb1, lb1, rt1, hlt, hrb, hlb, hrt);
        *(uint4*)(Sd)     = o0;
        *(uint4*)(Sd + 8) = o1;
    }
    __syncthreads();

    // ---- phase 2: 128oc x 32pix x 576K GEMM (16x16x32 fp16 MFMA) ----
    f32x4 acc[2];
#pragma unroll
    for (int e = 0; e < 4; ++e) {
        float bv = conv_b[16 * wv + lg * 4 + e];
        acc[0][e] = bv;
        acc[1][e] = bv;
    }
    const ushort* s0 = &S[(lr) * SST + lg * 8];
    const ushort* s1 = &S[(16 + lr) * SST + lg * 8];

#pragma unroll
    for (int ks = 0; ks < 18; ++ks) {
        int kk = ks * 32;
        half8t a0 = *(const half8t*)(wr0 + ks * 512);
        half8t b0 = *(const half8t*)(s0 + kk);
        half8t b1 = *(const half8t*)(s1 + kk);
        acc[0] = __builtin_amdgcn_mfma_f32_16x16x32_f16(a0, b0, acc[0], 0, 0, 0);
        acc[1] = __builtin_amdgcn_mfma_f32_16x16x32_f16(a0, b1, acc[1], 0, 0, 0);
    }

    float* ob = out + ((size_t)b * OCC * HH + oi) * WW + oj0;
#pragma unroll
    for (int p = 0; p < 2; ++p) {
#pragma unroll
        for (int e = 0; e < 4; ++e) {
            int oc  = 16 * wv + lg * 4 + e;
            int col = 16 * p + lr;
            ob[(size_t)oc * HWx + col] = acc[p][e];
        }
    }
}

extern "C" void kernel_launch(void* const* d_in, const int* in_sizes, int n_in,
                              void* d_out, int out_size, void* d_ws, size_t ws_size,
                              hipStream_t stream) {
    const float* x      = (const float*)d_in[0];
    const float* off_w  = (const float*)d_in[1];
    const float* off_b  = (const float*)d_in[2];
    const float* conv_w = (const float*)d_in[3];
    const float* conv_b = (const float*)d_in[4];
    float* out = (float*)d_out;

    char* w0 = (char*)d_ws;
    ushort* wbf   = (ushort*)w0;                       // 147456 B
    float*  offsT = (float*)(w0 + 147456);             // 9437184 B
    ushort* xTh   = (ushort*)(w0 + 147456 + 9437184);            // 16777216 B
    ushort* xTl   = (ushort*)(w0 + 147456 + 9437184 + 16777216); // 16777216 B
    ushort* woh   = (ushort*)(w0 + 147456 + 9437184 + 2 * 16777216);         // 36864 B
    ushort* wol   = (ushort*)(w0 + 147456 + 9437184 + 2 * 16777216 + 36864); // 36864 B

    kfront2<<<2480, 256, 0, stream>>>(x, xTh, xTl, conv_w, wbf, off_w, woh, wol);
    koffM<<<BB * HH, 256, 0, stream>>>(xTh, xTl, woh, wol, off_b, offsT);
    kmain23<<<BB * HH * 4, 512, 0, stream>>>(xTh, offsT, wbf, conv_b, out);
}

// Round 24
// 95.652 us; speedup vs baseline: 1.1756x; 1.1756x over previous
//
#include <hip/hip_runtime.h>
#include <hip/hip_fp16.h>

#define BB   8
#define CC   64
#define HH   128
#define WW   128
#define OCC  128
#define HWx  (HH*WW)
#define KTOT 576
#define SST  584    // ushort row stride: 576 + 8 (1168 B, 16B-multiple)

typedef __attribute__((ext_vector_type(8))) short short8t;
typedef __attribute__((ext_vector_type(8))) _Float16 half8t;
typedef __attribute__((ext_vector_type(4))) float f32x4;

static __device__ __forceinline__ ushort f2h(float f) {
    __half h = __float2half_rn(f);
    return __half_as_ushort(h);
}

// ---- K0c: off_w -> split fragment-ordered B tables (x1024), hi+lo fp16 ----
__global__ __launch_bounds__(256) void kprepw2(const float* __restrict__ ow,
                                               ushort* __restrict__ woh,
                                               ushort* __restrict__ wol) {
    int idx = blockIdx.x * 256 + threadIdx.x;  // 0..36863
    int t   = idx / 18432;              // 0=hi, 1=lo
    int r   = idx - t * 18432;
    int nt  = r / 9216;
    int r2  = r - nt * 9216;
    int ks  = r2 / 512;
    int r3  = r2 - ks * 512;
    int l   = r3 >> 3;
    int e   = r3 & 7;
    int k   = ks * 32 + (l >> 4) * 8 + e;
    int tap = k >> 6, c = k & 63;
    int ch  = nt * 16 + (l & 15);
    float val = (ch < 18) ? ow[ch * 576 + c * 9 + tap] * 1024.f : 0.f;
    __half h = __float2half_rn(val);
    if (t == 0) woh[r] = __half_as_ushort(h);
    else        wol[r] = f2h(val - __half2float(h));
}

// ---- KFRONT3: koffX (0..1023) + ktrans (1024..3071) + wf-prep (3072..3359)
__global__ __launch_bounds__(256) void kfront3(const float* __restrict__ x,
                                               const ushort* __restrict__ woh,
                                               const ushort* __restrict__ wol,
                                               const float* __restrict__ off_b,
                                               float* __restrict__ offsT,
                                               ushort* __restrict__ xTh,
                                               const float* __restrict__ cw,
                                               ushort* __restrict__ wf) {
    int bi  = blockIdx.x;
    int tid = threadIdx.x;

    if (bi < 1024) {
        // ---- role: offset conv via split-fp16 MFMA, A direct from x -------
        int b = bi & 7;
        int i = bi >> 3;
        int wv = tid >> 6;                 // wave: pixels [32wv, 32wv+32)
        int l  = tid & 63;
        int lr = l & 15, lg = l >> 4;
        const float* xb = x + (size_t)b * CC * HWx;

        f32x4 accA[2][2], accB[2][2];
#pragma unroll
        for (int mt = 0; mt < 2; ++mt)
#pragma unroll
            for (int nt = 0; nt < 2; ++nt)
#pragma unroll
                for (int e = 0; e < 4; ++e) { accA[mt][nt][e] = 0.f; accB[mt][nt][e] = 0.f; }

#pragma unroll
        for (int ks = 0; ks < 18; ++ks) {
            int tap = ks >> 1;
            int di = tap / 3, dj = tap - di * 3;
            int si = i + di - 1;
            bool sv = (si >= 0) && (si < HH);
            int c0 = (ks & 1) * 32 + lg * 8;

            half8t Bh0 = *(const half8t*)(woh + ((0 * 18 + ks) * 64 + l) * 8);
            half8t Bl0 = *(const half8t*)(wol + ((0 * 18 + ks) * 64 + l) * 8);
            half8t Bh1 = *(const half8t*)(woh + ((1 * 18 + ks) * 64 + l) * 8);
            half8t Bl1 = *(const half8t*)(wol + ((1 * 18 + ks) * 64 + l) * 8);

#pragma unroll
            for (int mt = 0; mt < 2; ++mt) {
                int j  = wv * 32 + mt * 16 + lr;
                int sj = j + dj - 1;
                bool v = sv && (sj >= 0) && (sj < WW);
                half8t Ah = {0, 0, 0, 0, 0, 0, 0, 0};
                half8t Al = {0, 0, 0, 0, 0, 0, 0, 0};
                if (v) {
                    const float* xp = xb + (size_t)c0 * HWx + si * WW + sj;
#pragma unroll
                    for (int e = 0; e < 8; ++e) {
                        float val = xp[(size_t)e * HWx];
                        _Float16 h = (_Float16)val;
                        Ah[e] = h;
                        Al[e] = (_Float16)((val - (float)h) * 2048.f);
                    }
                }
                accA[mt][0] = __builtin_amdgcn_mfma_f32_16x16x32_f16(Ah, Bh0, accA[mt][0], 0, 0, 0);
                accA[mt][0] = __builtin_amdgcn_mfma_f32_16x16x32_f16(Ah, Bl0, accA[mt][0], 0, 0, 0);
                accB[mt][0] = __builtin_amdgcn_mfma_f32_16x16x32_f16(Al, Bh0, accB[mt][0], 0, 0, 0);
                accA[mt][1] = __builtin_amdgcn_mfma_f32_16x16x32_f16(Ah, Bh1, accA[mt][1], 0, 0, 0);
                accA[mt][1] = __builtin_amdgcn_mfma_f32_16x16x32_f16(Ah, Bl1, accA[mt][1], 0, 0, 0);
                accB[mt][1] = __builtin_amdgcn_mfma_f32_16x16x32_f16(Al, Bh1, accB[mt][1], 0, 0, 0);
            }
        }

        const float sA = 1.f / 1024.f;
        const float sB = 1.f / (1024.f * 2048.f);
#pragma unroll
        for (int mt = 0; mt < 2; ++mt)
#pragma unroll
            for (int nt = 0; nt < 2; ++nt) {
                int ch = nt * 16 + lr;
                if (ch < 18) {
                    float bv = off_b[ch];
#pragma unroll
                    for (int e = 0; e < 4; ++e) {
                        int pix = wv * 32 + mt * 16 + lg * 4 + e;
                        float val = accA[mt][nt][e] * sA + accB[mt][nt][e] * sB + bv;
                        offsT[((size_t)(b * HWx) + i * WW + pix) * 18 + ch] = val;
                    }
                }
            }

    } else if (bi < 3072) {
        // ---- role: x NCHW fp32 -> xTh NHWC fp16 ----------------------------
        int bb = bi - 1024;
        int b  = bb >> 8;
        int p  = (bb & 255) * 64 + (tid & 63);
        int cg = tid >> 6;
        const float* xb = x + (size_t)b * CC * HWx + p;
        ushort* ob = xTh + ((size_t)b * HWx + p) * 64 + cg * 16;
        short8t v0, v1;
#pragma unroll
        for (int e = 0; e < 8; ++e) v0[e] = (short)f2h(xb[(size_t)(cg * 16 + e) * HWx]);
#pragma unroll
        for (int e = 0; e < 8; ++e) v1[e] = (short)f2h(xb[(size_t)(cg * 16 + 8 + e) * HWx]);
        *(short8t*)ob = v0;
        *(short8t*)(ob + 8) = v1;

    } else {
        // ---- role: conv_w -> fragment-ordered fp16 table -------------------
        int i = (bi - 3072) * 256 + tid;    // 0..73727
        int e  = i & 7;
        int t  = i >> 3;
        int l  = t & 63;
        int t2 = t >> 6;                    // wv*18 + ks
        int lr = l & 15, lg = l >> 4;
        int oc = (t2 / 18) * 16 + lr;
        int kg = (t2 % 18) * 32 + lg * 8 + e;
        int c = kg & 63, tap = kg >> 6;
        wf[i] = f2h(cw[oc * 576 + c * 9 + tap]);
    }
}

static __device__ __forceinline__ __half2 lerp_w(uint ltw, uint rbw, uint lbw, uint rtw,
                                                 __half2 hlt, __half2 hrb,
                                                 __half2 hlb, __half2 hrt) {
    __half2 a;
    a = __hmul2(hlt, __builtin_bit_cast(__half2, ltw));
    a = __hfma2(hrb, __builtin_bit_cast(__half2, rbw), a);
    a = __hfma2(hlb, __builtin_bit_cast(__half2, lbw), a);
    a = __hfma2(hrt, __builtin_bit_cast(__half2, rtw), a);
    return a;
}
static __device__ __forceinline__ uint4 lerp_u4(uint4 lt, uint4 rb, uint4 lb, uint4 rt,
                                                __half2 hlt, __half2 hrb,
                                                __half2 hlb, __half2 hrt) {
    uint4 o;
    o.x = __builtin_bit_cast(uint, lerp_w(lt.x, rb.x, lb.x, rt.x, hlt, hrb, hlb, hrt));
    o.y = __builtin_bit_cast(uint, lerp_w(lt.y, rb.y, lb.y, rt.y, hlt, hrb, hlb, hrt));
    o.z = __builtin_bit_cast(uint, lerp_w(lt.z, rb.z, lb.z, rt.z, hlt, hrb, hlb, hrt));
    o.w = __builtin_bit_cast(uint, lerp_w(lt.w, rb.w, lb.w, rt.w, hlt, hrb, hlb, hrt));
    return o;
}

// ---- K2: fused gather + MFMA; 16-ch grain + frag weights (R22 verbatim) ----
__global__ __launch_bounds__(512, 4) void kmain24(const ushort* __restrict__ xT,
                                                  const float* __restrict__ offsT,
                                                  const ushort* __restrict__ wf,
                                                  const float* __restrict__ conv_b,
                                                  float* __restrict__ out) {
    __shared__ __align__(16) ushort S[32 * SST];   // 37376 B
    int tid = threadIdx.x;                 // 0..511
    int bi  = blockIdx.x;
    int b   = bi & 7;                      // XCD-affine batch
    int rem = bi >> 3;                     // 0..511
    int oi  = rem >> 2;
    int oj0 = (rem & 3) * 32;

    const ushort* xTb  = xT + (size_t)b * HWx * 64;
    const float*  offb = offsT + (size_t)b * HWx * 18;

    int wv = tid >> 6;                     // wave 0..7: oc tile [16wv,16wv+16)
    int l  = tid & 63;
    int lr = l & 15;
    int lg = l >> 4;
    const ushort* wr0 = wf + ((size_t)(wv * 18) * 64 + l) * 8;

    // ---- phase 1: 1152 subtasks = (pix, tap, 16-ch), 2.25/thread ----
#pragma unroll
    for (int it = 0; it < 3; ++it) {
        int s = tid + it * 512;
        if (s >= 1152) break;
        int pix = s / 36;
        int rr  = s - pix * 36;
        int tap = rr >> 2;
        int cg2 = rr & 3;                  // 16-ch group
        int kr = tap / 3, kc = tap - kr * 3;
        int si = oi + ((kr == 0) ? -1 : 0);
        int sj = oj0 + pix + ((kc == 0) ? -1 : 0);
        ushort* Sd = &S[pix * SST + tap * 64 + cg2 * 16];

        if (si < 0 || sj < 0) {
            uint4 z = {0, 0, 0, 0};
            *(uint4*)Sd = z;
            *(uint4*)(Sd + 8) = z;
            continue;
        }
        int n    = ((kr == 0) ? 2 : kr - 1) * 3 + ((kc == 0) ? 2 : kc - 1);
        int pidx = si * WW + sj;
        float ox = offb[pidx * 18 + n];
        float oy = offb[pidx * 18 + 9 + n];
        float px = (float)si + ox;
        float py = (float)sj + oy;
        float fx = floorf(px), fy = floorf(py);
        float pxc   = fminf(fmaxf(px, 0.f), 127.f);
        float pyc   = fminf(fmaxf(py, 0.f), 127.f);
        float qltxf = fminf(fmaxf(fx, 0.f), 127.f);
        float qltyf = fminf(fmaxf(fy, 0.f), 127.f);
        float qrbxf = fminf(fmaxf(fx + 1.f, 0.f), 127.f);
        float qrbyf = fminf(fmaxf(fy + 1.f, 0.f), 127.f);
        int qltx = (int)qltxf, qlty = (int)qltyf;
        int qrbx = (int)qrbxf, qrby = (int)qrbyf;
        int co = cg2 * 16;
        const ushort* plt = xTb + (size_t)(qltx * WW + qlty) * 64 + co;
        const ushort* prb = xTb + (size_t)(qrbx * WW + qrby) * 64 + co;
        const ushort* plb = xTb + (size_t)(qltx * WW + qrby) * 64 + co;
        const ushort* prt = xTb + (size_t)(qrbx * WW + qlty) * 64 + co;
        uint4 lt0 = *(const uint4*)(plt);  uint4 lt1 = *(const uint4*)(plt + 8);
        uint4 rb0 = *(const uint4*)(prb);  uint4 rb1 = *(const uint4*)(prb + 8);
        uint4 lb0 = *(const uint4*)(plb);  uint4 lb1 = *(const uint4*)(plb + 8);
        uint4 rt0 = *(const uint4*)(prt);  uint4 rt1 = *(const uint4*)(prt + 8);

        float glt = (1.f + (qltxf - pxc)) * (1.f + (qltyf - pyc));
        float grb = (1.f - (qrbxf - pxc)) * (1.f - (qrbyf - pyc));
        float glb = (1.f + (qltxf - pxc)) * (1.f - (qrbyf - pyc));
        float grt = (1.f - (qrbxf - pxc)) * (1.f + (qltyf - pyc));
        __half2 hlt = __float2half2_rn(glt);
        __half2 hrb = __float2half2_rn(grb);
        __half2 hlb = __float2half2_rn(glb);
        __half2 hrt = __float2half2_rn(grt);

        uint4 o0 = lerp_u4(lt0, rb0, lb0, rt0, hlt, hrb, hlb, hrt);
        uint4 o1 = lerp_u4(lt1, rb1, lb1, rt1, hlt, hrb, hlb, hrt);
        *(uint4*)(Sd)     = o0;
        *(uint4*)(Sd + 8) = o1;
    }
    __syncthreads();

    // ---- phase 2: 128oc x 32pix x 576K GEMM (16x16x32 fp16 MFMA) ----
    f32x4 acc[2];
#pragma unroll
    for (int e = 0; e < 4; ++e) {
        float bv = conv_b[16 * wv + lg * 4 + e];
        acc[0][e] = bv;
        acc[1][e] = bv;
    }
    const ushort* s0 = &S[(lr) * SST + lg * 8];
    const ushort* s1 = &S[(16 + lr) * SST + lg * 8];

#pragma unroll
    for (int ks = 0; ks < 18; ++ks) {
        int kk = ks * 32;
        half8t a0 = *(const half8t*)(wr0 + ks * 512);
        half8t b0 = *(const half8t*)(s0 + kk);
        half8t b1 = *(const half8t*)(s1 + kk);
        acc[0] = __builtin_amdgcn_mfma_f32_16x16x32_f16(a0, b0, acc[0], 0, 0, 0);
        acc[1] = __builtin_amdgcn_mfma_f32_16x16x32_f16(a0, b1, acc[1], 0, 0, 0);
    }

    float* ob = out + ((size_t)b * OCC * HH + oi) * WW + oj0;
#pragma unroll
    for (int p = 0; p < 2; ++p) {
#pragma unroll
        for (int e = 0; e < 4; ++e) {
            int oc  = 16 * wv + lg * 4 + e;
            int col = 16 * p + lr;
            ob[(size_t)oc * HWx + col] = acc[p][e];
        }
    }
}

extern "C" void kernel_launch(void* const* d_in, const int* in_sizes, int n_in,
                              void* d_out, int out_size, void* d_ws, size_t ws_size,
                              hipStream_t stream) {
    const float* x      = (const float*)d_in[0];
    const float* off_w  = (const float*)d_in[1];
    const float* off_b  = (const float*)d_in[2];
    const float* conv_w = (const float*)d_in[3];
    const float* conv_b = (const float*)d_in[4];
    float* out = (float*)d_out;

    char* w0 = (char*)d_ws;
    ushort* wbf   = (ushort*)w0;                                 // 147456 B
    float*  offsT = (float*)(w0 + 147456);                       // 9437184 B
    ushort* xTh   = (ushort*)(w0 + 147456 + 9437184);            // 16777216 B
    ushort* woh   = (ushort*)(w0 + 147456 + 9437184 + 16777216);           // 36864 B
    ushort* wol   = (ushort*)(w0 + 147456 + 9437184 + 16777216 + 36864);   // 36864 B

    kprepw2<<<144, 256, 0, stream>>>(off_w, woh, wol);
    kfront3<<<3360, 256, 0, stream>>>(x, woh, wol, off_b, offsT, xTh, conv_w, wbf);
    kmain24<<<BB * HH * 4, 512, 0, stream>>>(xTh, offsT, wbf, conv_b, out);
}